// Round 1
// baseline (31318.237 us; speedup 1.0000x reference)
//
#include <hip/hip_runtime.h>
#include <hip/hip_fp16.h>
#include <stdint.h>

#define NWG 256
#define TPB 256
#define KTOT 2176                      // 2048 (W_res) + 64 (W_in hi) + 64 (W_in lo)
#define WT_ROWSTRIDE 4352u             // bytes per n-row of W tile (2176 * 2B)
#define CBUF_OFF 139264                // 32 * 4352
#define CBUF_STRIDE 40u                // halfs per row (80B, keeps 16B alignment, spreads banks)
#define LDS_BYTES (139264 + 64*40*2)   // 144384 B  (< 160 KiB)

typedef _Float16 f16;
typedef f16   half8 __attribute__((ext_vector_type(8)));
typedef float f32x4 __attribute__((ext_vector_type(4)));

// Swizzled byte address of W tile element [n][k]  (n in [0,32), k in [0,2176)).
// Row stride is a multiple of 128B -> all n collide on the same banks; XOR of
// (n&7) into byte bits 4..6 spreads 16 lanes over 8 16B-slots = 2-way (free).
__device__ __forceinline__ uint32_t wt_addr(uint32_t n, uint32_t k) {
  return (n * WT_ROWSTRIDE + k * 2u) ^ ((n & 7u) << 4);
}

// Sense-reversing grid barrier. cnt/gen live in d_ws (agent-scope atomics -> LLC).
__device__ __forceinline__ void gridbar(uint32_t* cnt, uint32_t* gen) {
  __syncthreads();        // all threads' stores issued & vm-drained
  __threadfence();        // release: write back L2 -> LLC (cross-XCD visibility)
  if (threadIdx.x == 0) {
    uint32_t g = __hip_atomic_load(gen, __ATOMIC_RELAXED, __HIP_MEMORY_SCOPE_AGENT);
    uint32_t a = __hip_atomic_fetch_add(cnt, 1u, __ATOMIC_ACQ_REL, __HIP_MEMORY_SCOPE_AGENT);
    if (a == NWG - 1u) {
      __hip_atomic_store(cnt, 0u, __ATOMIC_RELAXED, __HIP_MEMORY_SCOPE_AGENT);
      __hip_atomic_store(gen, g + 1u, __ATOMIC_RELEASE, __HIP_MEMORY_SCOPE_AGENT);
    } else {
      while (__hip_atomic_load(gen, __ATOMIC_RELAXED, __HIP_MEMORY_SCOPE_AGENT) == g)
        __builtin_amdgcn_s_sleep(8);
    }
  }
  __syncthreads();
  __threadfence();        // acquire: invalidate L1/L2 so h reads are fresh
}

extern "C" __global__ void __launch_bounds__(TPB, 1)
esn_persistent_kernel(const float* __restrict__ x,
                      const float* __restrict__ Win,
                      const float* __restrict__ Wres,
                      const float* __restrict__ Wout,
                      const float* __restrict__ bout,
                      float* __restrict__ out,
                      f16* __restrict__ h16,
                      uint32_t* __restrict__ bar)
{
  extern __shared__ char smem[];
  f16* cbuf = (f16*)(smem + CBUF_OFF);

  const uint32_t tid = threadIdx.x;
  const uint32_t wg  = blockIdx.x;
  // XCD-aware mapping: blocks round-robin across 8 XCDs; put both XCDs 2g,2g+1
  // on batch-group g so each XCD's 32 WGs share the same 64 h-rows in its L2.
  const uint32_t xcd = wg & 7u, sl = wg >> 3;
  const uint32_t grp = xcd >> 1;               // batch group 0..3 (64 rows each)
  const uint32_t cb  = sl * 2u + (xcd & 1u);   // column block 0..63 (32 cols each)
  const uint32_t b0  = grp * 64u;
  const uint32_t n0  = cb * 32u;

  // --- init barrier words from 0xAA poison (idempotent CAS; safe mid-count) ---
  if (tid == 0) {
    uint32_t e0 = 0xAAAAAAAAu;
    __hip_atomic_compare_exchange_strong(&bar[0], &e0, 0u, __ATOMIC_RELAXED,
                                         __ATOMIC_RELAXED, __HIP_MEMORY_SCOPE_AGENT);
    uint32_t e1 = 0xAAAAAAAAu;
    __hip_atomic_compare_exchange_strong(&bar[32], &e1, 0u, __ATOMIC_RELAXED,
                                         __ATOMIC_RELAXED, __HIP_MEMORY_SCOPE_AGENT);
  }

  // --- stage W_res column slice into LDS (f16, swizzled), coalesced reads ---
  for (uint32_t e = tid; e < 2048u * 32u; e += TPB) {
    uint32_t n = e & 31u, k = e >> 5;
    *(f16*)(smem + wt_addr(n, k)) = (f16)Wres[k * 2048u + n0 + n];
  }
  // --- stage W_in slice split hi/lo (rows 2048.. and 2112..) ---
  for (uint32_t e = tid; e < 64u * 32u; e += TPB) {
    uint32_t n = e & 31u, i = e >> 5;
    float v = Win[i * 2048u + n0 + n];
    f16 hi = (f16)v;
    f16 lo = (f16)(v - (float)hi);
    *(f16*)(smem + wt_addr(n, 2048u + i)) = hi;
    *(f16*)(smem + wt_addr(n, 2112u + i)) = lo;
  }
  // --- zero own h16 slice (64 rows x 32 cols) ---
  {
    uint32_t row = tid >> 2, ch = tid & 3u;
    uint4 z = make_uint4(0u, 0u, 0u, 0u);
    *(uint4*)(h16 + (b0 + row) * 2048u + n0 + ch * 8u) = z;
  }
  // --- zero output (d_out is poisoned each launch) ---
  if (cb == 0) {
    for (uint32_t e = tid; e < 640u; e += TPB) out[b0 * 10u + e] = 0.0f;
  }

  gridbar(&bar[0], &bar[32]);   // barrier 0: weights staged, h zeroed, out zeroed

  // --- wave identity: 4 waves, each computes a 32(M) x 16(N) output tile ---
  const uint32_t l  = tid & 63u, w = tid >> 6;
  const uint32_t wm = w >> 1, nw = w & 1u;
  const uint32_t lrow = l & 15u;
  const uint32_t lk   = (l >> 4) * 8u;          // k-chunk offset within 32
  const uint32_t rA0  = b0 + wm * 32u + lrow;   // A rows for the two M-tiles
  const uint32_t rA1  = rA0 + 16u;
  const uint32_t nB   = nw * 16u + lrow;        // B column within our 32-col slice

  f32x4 m0 = {0.f, 0.f, 0.f, 0.f};   // f32 master state (this lane's 8 h elems)
  f32x4 m1 = {0.f, 0.f, 0.f, 0.f};

  const f16* hp0 = h16 + rA0 * 2048u + lk;
  const f16* hp1 = h16 + rA1 * 2048u + lk;

  for (int t = 0; t < 512; ++t) {
    f32x4 a0 = {0.f, 0.f, 0.f, 0.f};
    f32x4 a1 = {0.f, 0.f, 0.f, 0.f};

    // h @ W_res : K = 2048 in 64 chunks of 32
    #pragma unroll 8
    for (uint32_t kk = 0; kk < 64u; ++kk) {
      half8 af0 = *(const half8*)(hp0 + kk * 32u);
      half8 af1 = *(const half8*)(hp1 + kk * 32u);
      half8 bf  = *(const half8*)(smem + wt_addr(nB, kk * 32u + lk));
      a0 = __builtin_amdgcn_mfma_f32_16x16x32_f16(af0, bf, a0, 0, 0, 0);
      a1 = __builtin_amdgcn_mfma_f32_16x16x32_f16(af1, bf, a1, 0, 0, 0);
    }

    // x_t @ W_in, split precision: xh*Wh + xl*Wh + xh*Wl  (~f32 accuracy)
    const float* px0 = x + (rA0 * 512u + (uint32_t)t) * 64u + lk;
    const float* px1 = x + (rA1 * 512u + (uint32_t)t) * 64u + lk;
    #pragma unroll
    for (uint32_t kx = 0; kx < 2u; ++kx) {
      half8 xh0, xl0, xh1, xl1;
      #pragma unroll
      for (uint32_t j = 0; j < 8u; ++j) {
        float v0 = px0[kx * 32u + j];
        f16 h0 = (f16)v0; xh0[j] = h0; xl0[j] = (f16)(v0 - (float)h0);
        float v1 = px1[kx * 32u + j];
        f16 h1 = (f16)v1; xh1[j] = h1; xl1[j] = (f16)(v1 - (float)h1);
      }
      half8 bh = *(const half8*)(smem + wt_addr(nB, 2048u + kx * 32u + lk));
      half8 bl = *(const half8*)(smem + wt_addr(nB, 2112u + kx * 32u + lk));
      a0 = __builtin_amdgcn_mfma_f32_16x16x32_f16(xh0, bh, a0, 0, 0, 0);
      a1 = __builtin_amdgcn_mfma_f32_16x16x32_f16(xh1, bh, a1, 0, 0, 0);
      a0 = __builtin_amdgcn_mfma_f32_16x16x32_f16(xl0, bh, a0, 0, 0, 0);
      a1 = __builtin_amdgcn_mfma_f32_16x16x32_f16(xl1, bh, a1, 0, 0, 0);
      a0 = __builtin_amdgcn_mfma_f32_16x16x32_f16(xh0, bl, a0, 0, 0, 0);
      a1 = __builtin_amdgcn_mfma_f32_16x16x32_f16(xh1, bl, a1, 0, 0, 0);
    }

    // leaky update in f32; stage f16 copy to cbuf for coalesced global store
    {
      const uint32_t ccol = nw * 16u + lrow;
      const uint32_t r0   = wm * 32u + (l >> 4) * 4u;   // C row = (lane>>4)*4 + reg
      #pragma unroll
      for (uint32_t r = 0; r < 4u; ++r) {
        m0[r] = 0.5f * m0[r] + 0.5f * tanhf(a0[r]);
        m1[r] = 0.5f * m1[r] + 0.5f * tanhf(a1[r]);
        cbuf[(r0 + r) * CBUF_STRIDE + ccol]        = (f16)m0[r];
        cbuf[(r0 + 16u + r) * CBUF_STRIDE + ccol]  = (f16)m1[r];
      }
    }
    __syncthreads();
    if (t != 511) {   // last state is never read back; skip store + barrier
      uint32_t row = tid >> 2, ch = tid & 3u;
      uint4 v = *(const uint4*)(cbuf + row * CBUF_STRIDE + ch * 8u);
      *(uint4*)(h16 + (b0 + row) * 2048u + n0 + ch * 8u) = v;
      gridbar(&bar[0], &bar[32]);
    }
  }

  // --- readout: out = h_last @ W_out + b_out, partials per WG via atomicAdd ---
  __syncthreads();
  float* rb = (float*)smem;                     // reuse W area: [64][33] f32
  {
    const uint32_t ccol = nw * 16u + lrow;
    const uint32_t r0   = wm * 32u + (l >> 4) * 4u;
    #pragma unroll
    for (uint32_t r = 0; r < 4u; ++r) {
      rb[(r0 + r) * 33u + ccol]       = m0[r];
      rb[(r0 + 16u + r) * 33u + ccol] = m1[r];
    }
  }
  __syncthreads();
  for (uint32_t e = tid; e < 640u; e += TPB) {
    uint32_t b = e / 10u, o = e - b * 10u;
    float s = 0.0f;
    #pragma unroll
    for (uint32_t j = 0; j < 32u; ++j)
      s += rb[b * 33u + j] * Wout[(n0 + j) * 10u + o];
    if (cb == 0) s += bout[o];                  // bias added exactly once per (b,o)
    atomicAdd(&out[(b0 + b) * 10u + o], s);
  }
}

extern "C" void kernel_launch(void* const* d_in, const int* in_sizes, int n_in,
                              void* d_out, int out_size, void* d_ws, size_t ws_size,
                              hipStream_t stream) {
  (void)in_sizes; (void)n_in; (void)out_size; (void)ws_size;
  const float* x    = (const float*)d_in[0];
  const float* Win  = (const float*)d_in[1];
  const float* Wres = (const float*)d_in[2];
  const float* Wout = (const float*)d_in[3];
  const float* bout = (const float*)d_in[4];
  float* out = (float*)d_out;

  f16*      h16 = (f16*)d_ws;                                  // 256*2048*2B = 1 MiB
  uint32_t* bar = (uint32_t*)((char*)d_ws + 256u * 2048u * 2u); // cnt @ +0, gen @ +128B

  // allow >64 KiB dynamic LDS (141 KiB); idempotent, host-side, capture-safe
  hipFuncSetAttribute((const void*)esn_persistent_kernel,
                      hipFuncAttributeMaxDynamicSharedMemorySize, LDS_BYTES);

  hipLaunchKernelGGL(esn_persistent_kernel, dim3(NWG), dim3(TPB), LDS_BYTES, stream,
                     x, Win, Wres, Wout, bout, out, h16, bar);
}

// Round 4
// 8545.968 us; speedup vs baseline: 3.6647x; 3.6647x over previous
//
#include <hip/hip_runtime.h>
#include <stdint.h>

// ESN forward, persistent kernel, MI355X.
// Geometry: 8 groups (== XCDs under round-robin) x 32 WGs. Group g owns batch
// rows [g*32, g*32+32); WG cb in group owns reservoir cols [cb*64, cb*64+64).
// 4 waves/WG, split-K: wave wv owns K-slice [wv*512, wv*512+512) of h @ W_res.
// W_res slice lives entirely in VGPRs (256/lane). h is exchanged per step via
// global double buffers + per-group counter barrier (agent-scope fences, so
// correctness does NOT depend on the WG->XCD mapping; mapping is perf-only).

#define NWG 256
#define TPB 256
#define LDS_BYTES 131072u   // 2 sub-chunk bufs x 4 waves x 16KB

typedef _Float16 f16;
typedef f16   half8 __attribute__((ext_vector_type(8)));
typedef float f32x4 __attribute__((ext_vector_type(4)));

// async global->LDS DMA: 64 lanes x 16B; LDS dest = wave-uniform base + lane*16
__device__ __forceinline__ void gload_lds16(const void* g, void* lds) {
  __builtin_amdgcn_global_load_lds(
      (const __attribute__((address_space(1))) uint32_t*)g,
      (__attribute__((address_space(3))) uint32_t*)lds, 16, 0, 0);
}

__device__ __forceinline__ float ftanh(float z) {
  z = fminf(15.0f, fmaxf(-15.0f, z));   // tanh(15)=1-2e-13
  float e = __expf(2.0f * z);
  return (e - 1.0f) * __builtin_amdgcn_rcpf(e + 1.0f);
}

// one-shot global barrier for init (poison-tolerant: callers CAS-init words)
__device__ __forceinline__ void flatbar(uint32_t* cnt, uint32_t* gen) {
  __syncthreads();
  __threadfence();
  if (threadIdx.x == 0) {
    uint32_t g = __hip_atomic_load(gen, __ATOMIC_RELAXED, __HIP_MEMORY_SCOPE_AGENT);
    uint32_t a = __hip_atomic_fetch_add(cnt, 1u, __ATOMIC_ACQ_REL, __HIP_MEMORY_SCOPE_AGENT);
    if (a == NWG - 1u) {
      __hip_atomic_store(cnt, 0u, __ATOMIC_RELAXED, __HIP_MEMORY_SCOPE_AGENT);
      __hip_atomic_store(gen, g + 1u, __ATOMIC_RELEASE, __HIP_MEMORY_SCOPE_AGENT);
    } else {
      while (__hip_atomic_load(gen, __ATOMIC_RELAXED, __HIP_MEMORY_SCOPE_AGENT) == g)
        __builtin_amdgcn_s_sleep(8);
    }
  }
  __syncthreads();
  __threadfence();
}

#define WAITVM(n) asm volatile("s_waitcnt vmcnt(" #n ")" ::: "memory")

extern "C" __global__ void __launch_bounds__(TPB, 1)
esn_persistent_kernel(const float* __restrict__ x,
                      const float* __restrict__ Win,
                      const float* __restrict__ Wres,
                      const float* __restrict__ Wout,
                      const float* __restrict__ bout,
                      float* __restrict__ out,
                      f16* __restrict__ hga,        // h, read at even t
                      f16* __restrict__ hgb,        // h, read at odd t
                      uint32_t* __restrict__ scnt,  // per-(step,group) counters
                      uint32_t* __restrict__ fbar)  // init barrier
{
  extern __shared__ char smem[];
  const uint32_t tid = threadIdx.x, wg = blockIdx.x;
  const uint32_t g  = wg & 7u;           // == XCD under round-robin dispatch
  const uint32_t cb = wg >> 3u;          // column block 0..31
  const uint32_t b0 = g * 32u, n0 = cb * 64u;
  const uint32_t l = tid & 63u, wv = tid >> 6u;
  const uint32_t lrow = l & 15u, q = l >> 4u, kb = q * 8u;
  const uint32_t orow = tid >> 3u, ocol = (tid & 7u) * 8u;  // ownership layout

  char* lb0 = smem + wv * 16384u;             // this wave's sub-chunk buf 0
  char* lb1 = smem + 65536u + wv * 16384u;    // this wave's sub-chunk buf 1

  // ---- init from 0xAA poison ----
  if (tid == 0) {
    uint32_t e0 = 0xAAAAAAAAu;
    __hip_atomic_compare_exchange_strong(&fbar[0], &e0, 0u, __ATOMIC_RELAXED,
                                         __ATOMIC_RELAXED, __HIP_MEMORY_SCOPE_AGENT);
    uint32_t e1 = 0xAAAAAAAAu;
    __hip_atomic_compare_exchange_strong(&fbar[32], &e1, 0u, __ATOMIC_RELAXED,
                                         __ATOMIC_RELAXED, __HIP_MEMORY_SCOPE_AGENT);
  }
  *(uint4*)(hga + (size_t)(b0 + orow) * 2048u + n0 + ocol) = make_uint4(0u, 0u, 0u, 0u);
  if (tid < 64u) scnt[wg * 64u + tid] = 0u;    // 256 WGs x 64 words, disjoint
  if (cb == 0)
    for (uint32_t e = tid; e < 320u; e += TPB) out[b0 * 10u + e] = 0.0f;

  // ---- W_res slice -> VGPRs (persist 512 steps): wave's 512-K x 64-N ----
  half8 wb[16][4];                 // 256 VGPRs
  #pragma unroll
  for (uint32_t kk = 0; kk < 16u; ++kk)
    #pragma unroll
    for (uint32_t nt = 0; nt < 4u; ++nt)
      #pragma unroll
      for (uint32_t j = 0; j < 8u; ++j)
        wb[kk][nt][j] = (f16)Wres[(size_t)(wv * 512u + kk * 32u + kb + j) * 2048u
                                  + n0 + nt * 16u + lrow];
  // ---- W_in split hi/lo, this wave's 16-col group (nt == wv) ----
  half8 wiH[2], wiL[2];
  #pragma unroll
  for (uint32_t kx = 0; kx < 2u; ++kx)
    #pragma unroll
    for (uint32_t j = 0; j < 8u; ++j) {
      float v = Win[(size_t)(kx * 32u + kb + j) * 2048u + n0 + wv * 16u + lrow];
      f16 hh = (f16)v; wiH[kx][j] = hh; wiL[kx][j] = (f16)(v - (float)hh);
    }

  f32x4 acc[2][4], xa[2];
  #pragma unroll
  for (uint32_t mt = 0; mt < 2u; ++mt) {
    xa[mt] = (f32x4){0.f, 0.f, 0.f, 0.f};
    #pragma unroll
    for (uint32_t nt = 0; nt < 4u; ++nt) acc[mt][nt] = (f32x4){0.f, 0.f, 0.f, 0.f};
  }
  float m8[8];
  #pragma unroll
  for (int j = 0; j < 8; ++j) m8[j] = 0.0f;

  // ---- swizzle precompute (XOR involution; inverse pre-applied to global src
  // because global_load_lds writes LDS linearly -- both-sides-or-neither) ----
  // LDS holds h[r][c-byte] at r*512 + (c ^ ((r&7)<<4)), c in [0,512).
  const uint32_t ri = l >> 5u;                               // row parity in DMA pair
  const uint32_t cc = ((l & 31u) * 16u) ^ (ri << 4u);        // stage-side byte col
  const uint32_t bc = (q * 16u) ^ ((l & 7u) << 4u);          // read-side XOR term
  const uint32_t rb0 = lrow * 512u, rb1 = (16u + lrow) * 512u;

#define STAGE(sb, lb) { \
    const char* gsx = (const char*)hr + (size_t)(b0 + ri) * 4096u \
                      + wv * 1024u + (sb) * 512u; \
    _Pragma("unroll") \
    for (uint32_t d = 0; d < 16u; ++d) \
      gload_lds16(gsx + (size_t)d * 8192u + (cc ^ (((2u * d) & 7u) << 4u)), \
                  (lb) + d * 1024u); }

#define GSUB(lb, base) { \
    _Pragma("unroll") \
    for (uint32_t kk = 0; kk < 8u; ++kk) { \
      half8 a0 = *(const half8*)((lb) + rb0 + ((kk * 64u) ^ bc)); \
      half8 a1 = *(const half8*)((lb) + rb1 + ((kk * 64u) ^ bc)); \
      _Pragma("unroll") \
      for (uint32_t nt = 0; nt < 4u; ++nt) { \
        acc[0][nt] = __builtin_amdgcn_mfma_f32_16x16x32_f16(a0, wb[(base) + kk][nt], acc[0][nt], 0, 0, 0); \
        acc[1][nt] = __builtin_amdgcn_mfma_f32_16x16x32_f16(a1, wb[(base) + kk][nt], acc[1][nt], 0, 0, 0); \
      } } }

  // x_t @ W_in (split f16: xh*Wh + xl*Wh + xh*Wl), this wave's 16 cols only
#define XPROJ(tt) { \
    _Pragma("unroll") \
    for (uint32_t mt = 0; mt < 2u; ++mt) { \
      const float* px = x + ((size_t)(b0 + mt * 16u + lrow) * 512u + (uint32_t)(tt)) * 64u + kb; \
      _Pragma("unroll") \
      for (uint32_t kx = 0; kx < 2u; ++kx) { \
        float4 va = *(const float4*)(px + kx * 32u); \
        float4 vb = *(const float4*)(px + kx * 32u + 4u); \
        float fv[8] = {va.x, va.y, va.z, va.w, vb.x, vb.y, vb.z, vb.w}; \
        half8 xh, xl; \
        _Pragma("unroll") \
        for (int j = 0; j < 8; ++j) { \
          f16 hh = (f16)fv[j]; xh[j] = hh; xl[j] = (f16)(fv[j] - (float)hh); } \
        xa[mt] = __builtin_amdgcn_mfma_f32_16x16x32_f16(xh, wiH[kx], xa[mt], 0, 0, 0); \
        xa[mt] = __builtin_amdgcn_mfma_f32_16x16x32_f16(xl, wiH[kx], xa[mt], 0, 0, 0); \
        xa[mt] = __builtin_amdgcn_mfma_f32_16x16x32_f16(xh, wiL[kx], xa[mt], 0, 0, 0); \
      } } }

  XPROJ(0);                       // t=0 projection hides flatbar skew
  flatbar(&fbar[0], &fbar[32]);   // weights staged, h zeroed, out zeroed

  float* part = (float*)smem;     // split-K partials [128][68] f32 (overlay bufs)

  for (int t = 0; t < 512; ++t) {
    const f16* hr = (t & 1) ? hgb : hga;
    f16*       hw = (t & 1) ? hga : hgb;

    // ---- h @ W_res: self-synchronized per wave (own DMAs -> own buf) ----
    STAGE(0u, lb0);
    STAGE(1u, lb1);
    WAITVM(16);                   // sub-chunk 0 landed (exactly 32 were in flight)
    GSUB(lb0, 0u);
    WAITVM(0);                    // sub-chunk 1 landed
    GSUB(lb1, 8u);
    __syncthreads();              // S1: all waves done reading staging bufs

    // ---- write split-K partials (+ fold x-projection where nt==wv) ----
    #pragma unroll
    for (uint32_t mt = 0; mt < 2u; ++mt)
      #pragma unroll
      for (uint32_t nt = 0; nt < 4u; ++nt)
        #pragma unroll
        for (uint32_t r = 0; r < 4u; ++r) {
          float v = acc[mt][nt][r] + ((nt == wv) ? xa[mt][r] : 0.0f);
          part[(wv * 32u + mt * 16u + q * 4u + r) * 68u + nt * 16u + lrow] = v;
          acc[mt][nt][r] = 0.0f;
        }
    #pragma unroll
    for (uint32_t mt = 0; mt < 2u; ++mt)
      #pragma unroll
      for (uint32_t r = 0; r < 4u; ++r) xa[mt][r] = 0.0f;
    __syncthreads();              // S2: partials visible

    // ---- reduce 4 partials, tanh, leaky update (ownership layout) ----
    #pragma unroll
    for (int j = 0; j < 8; ++j) {
      float s = part[(orow)       * 68u + ocol + j]
              + part[(32u + orow) * 68u + ocol + j]
              + part[(64u + orow) * 68u + ocol + j]
              + part[(96u + orow) * 68u + ocol + j];
      m8[j] = 0.5f * m8[j] + 0.5f * ftanh(s);
    }

    if (t != 511) {
      // publish f16 state (16B coalesced per thread)
      half8 hv;
      #pragma unroll
      for (int j = 0; j < 8; ++j) hv[j] = (f16)m8[j];
      *(uint4*)(hw + (size_t)(b0 + orow) * 2048u + n0 + ocol) = *(uint4*)&hv;
      __syncthreads();            // S3: all threads' stores vm-drained
      uint32_t* cptr = scnt + ((uint32_t)t * 8u + g) * 4u;  // fresh ctr per step
      if (tid == 0) {
        __builtin_amdgcn_fence(__ATOMIC_RELEASE, "agent");  // wb L2 (cross-XCD safe)
        __hip_atomic_fetch_add(cptr, 1u, __ATOMIC_RELAXED, __HIP_MEMORY_SCOPE_AGENT);
      }
      XPROJ(t + 1);               // overlap barrier latency with next x-proj
      if (tid == 0)
        while (__hip_atomic_load(cptr, __ATOMIC_RELAXED, __HIP_MEMORY_SCOPE_AGENT) < 32u)
          __builtin_amdgcn_s_sleep(2);
      __syncthreads();            // S4
      __builtin_amdgcn_fence(__ATOMIC_ACQUIRE, "agent");    // inv L1(+L2 nonlocal)
    }
  }

  // ---- readout: out = h_last @ W_out + b_out ----
  {
    float* rsc = (float*)(smem + 40960u);   // [256 threads][10] f32, disjoint
    float ps[10];
    #pragma unroll
    for (int o = 0; o < 10; ++o) ps[o] = 0.0f;
    #pragma unroll
    for (int j = 0; j < 8; ++j) {
      float mj = m8[j];
      #pragma unroll
      for (int o = 0; o < 10; ++o)
        ps[o] += mj * Wout[(size_t)(n0 + ocol + j) * 10u + o];
    }
    #pragma unroll
    for (int o = 0; o < 10; ++o) rsc[tid * 10u + o] = ps[o];
    __syncthreads();
    for (uint32_t e = tid; e < 320u; e += TPB) {
      uint32_t row = e / 10u, o = e - row * 10u;
      float s = 0.0f;
      #pragma unroll
      for (uint32_t k = 0; k < 8u; ++k) s += rsc[(row * 8u + k) * 10u + o];
      if (cb == 0) s += bout[o];          // bias exactly once per (b,o)
      atomicAdd(&out[(size_t)(b0 + row) * 10u + o], s);
    }
  }
}

extern "C" void kernel_launch(void* const* d_in, const int* in_sizes, int n_in,
                              void* d_out, int out_size, void* d_ws, size_t ws_size,
                              hipStream_t stream) {
  (void)in_sizes; (void)n_in; (void)out_size; (void)ws_size;
  const float* x    = (const float*)d_in[0];
  const float* Win  = (const float*)d_in[1];
  const float* Wres = (const float*)d_in[2];
  const float* Wout = (const float*)d_in[3];
  const float* bout = (const float*)d_in[4];
  float* out = (float*)d_out;

  f16*      hga  = (f16*)d_ws;                                   // 1 MiB
  f16*      hgb  = (f16*)((char*)d_ws + (1u << 20));             // 1 MiB
  uint32_t* scnt = (uint32_t*)((char*)d_ws + (2u << 20));        // 64 KiB counters
  uint32_t* fbar = (uint32_t*)((char*)d_ws + (2u << 20) + (64u << 10)); // 256 B

  hipFuncSetAttribute((const void*)esn_persistent_kernel,
                      hipFuncAttributeMaxDynamicSharedMemorySize, LDS_BYTES);

  hipLaunchKernelGGL(esn_persistent_kernel, dim3(NWG), dim3(TPB), LDS_BYTES, stream,
                     x, Win, Wres, Wout, bout, out, hga, hgb, scnt, fbar);
}

// Round 9
// 3277.962 us; speedup vs baseline: 9.5542x; 2.6071x over previous
//
#include <hip/hip_runtime.h>
#include <stdint.h>

// ESN forward, persistent kernel, MI355X — fence-free LLC exchange version.
// Geometry: 8 groups x 32 WGs. Group g owns batch rows [g*32, g*32+32); WG cb
// owns reservoir cols [cb*64, cb*64+64). 4 waves/WG, split-K: wave wv owns
// K-slice [wv*512, wv*512+512) of h @ W_res. W_res slice register-resident
// (256 VGPR/lane). h exchanged per step via global double buffers:
//   publish: global_store_dwordx4 sc0 sc1  (system-scope write-through -> LLC)
//   stage:   global_load_lds aux=0x11      (system-scope: bypass L1+L2 -> LLC)
//   sync:    monotonic per-group counter, relaxed agent atomics, NO fences.
// Correct under any WG->XCD mapping (coherence point is the LLC per-access).

#define NWG 256
#define TPB 256
#define LDS_BYTES 131072u   // 2 sub-chunk bufs x 4 waves x 16KB

typedef _Float16 f16;
typedef f16      half8 __attribute__((ext_vector_type(8)));
typedef float    f32x4 __attribute__((ext_vector_type(4)));
typedef uint32_t u32x4 __attribute__((ext_vector_type(4)));   // asm-friendly 16B payload

// async global->LDS DMA, LLC-coherent: SC0|SC1 (CPol bit0|bit4 = 0x11) bypasses L1+L2
__device__ __forceinline__ void gload_lds16_llc(const void* g, void* lds) {
  __builtin_amdgcn_global_load_lds(
      (const __attribute__((address_space(1))) uint32_t*)g,
      (__attribute__((address_space(3))) uint32_t*)lds, 16, 0, 0x11);
}

// 16B write-through store: visible in LLC once vmcnt retires (no wbl2 needed).
// Payload must be an ext_vector (direct VGPR quad) — structs are rejected.
__device__ __forceinline__ void store16_llc(void* p, u32x4 v) {
  asm volatile("global_store_dwordx4 %0, %1, off sc0 sc1"
               :: "v"(p), "v"(v) : "memory");
}

__device__ __forceinline__ float ftanh(float z) {
  z = fminf(15.0f, fmaxf(-15.0f, z));   // tanh(15)=1-2e-13
  float e = __expf(2.0f * z);
  return (e - 1.0f) * __builtin_amdgcn_rcpf(e + 1.0f);
}

// one-shot global barrier for init (its threadfences also flush init stores)
__device__ __forceinline__ void flatbar(uint32_t* cnt, uint32_t* gen) {
  __syncthreads();
  __threadfence();
  if (threadIdx.x == 0) {
    uint32_t g = __hip_atomic_load(gen, __ATOMIC_RELAXED, __HIP_MEMORY_SCOPE_AGENT);
    uint32_t a = __hip_atomic_fetch_add(cnt, 1u, __ATOMIC_ACQ_REL, __HIP_MEMORY_SCOPE_AGENT);
    if (a == NWG - 1u) {
      __hip_atomic_store(cnt, 0u, __ATOMIC_RELAXED, __HIP_MEMORY_SCOPE_AGENT);
      __hip_atomic_store(gen, g + 1u, __ATOMIC_RELEASE, __HIP_MEMORY_SCOPE_AGENT);
    } else {
      while (__hip_atomic_load(gen, __ATOMIC_RELAXED, __HIP_MEMORY_SCOPE_AGENT) == g)
        __builtin_amdgcn_s_sleep(8);
    }
  }
  __syncthreads();
  __threadfence();
}

#define WAITVM(n) asm volatile("s_waitcnt vmcnt(" #n ")" ::: "memory")

extern "C" __global__ void __launch_bounds__(TPB, 1)
esn_persistent_kernel(const float* __restrict__ x,
                      const float* __restrict__ Win,
                      const float* __restrict__ Wres,
                      const float* __restrict__ Wout,
                      const float* __restrict__ bout,
                      float* __restrict__ out,
                      f16* __restrict__ hga,        // h, read at even t
                      f16* __restrict__ hgb,        // h, read at odd t
                      uint32_t* __restrict__ scnt,  // 8 monotonic group counters (64B apart)
                      uint32_t* __restrict__ fbar)  // init barrier
{
  extern __shared__ char smem[];
  const uint32_t tid = threadIdx.x, wg = blockIdx.x;
  const uint32_t g  = wg & 7u;           // group (== XCD under round-robin)
  const uint32_t cb = wg >> 3u;          // column block 0..31
  const uint32_t b0 = g * 32u, n0 = cb * 64u;
  const uint32_t l = tid & 63u, wv = tid >> 6u;
  const uint32_t lrow = l & 15u, q = l >> 4u, kb = q * 8u;
  const uint32_t orow = tid >> 3u, ocol = (tid & 7u) * 8u;  // ownership layout

  char* lb0 = smem + wv * 16384u;             // this wave's sub-chunk buf 0
  char* lb1 = smem + 65536u + wv * 16384u;    // this wave's sub-chunk buf 1
  uint32_t* gcnt = scnt + g * 16u;            // this group's monotonic counter

  // ---- init from 0xAA poison (idempotent CAS races are benign) ----
  if (tid == 0) {
    uint32_t e0 = 0xAAAAAAAAu;
    __hip_atomic_compare_exchange_strong(&fbar[0], &e0, 0u, __ATOMIC_RELAXED,
                                         __ATOMIC_RELAXED, __HIP_MEMORY_SCOPE_AGENT);
    uint32_t e1 = 0xAAAAAAAAu;
    __hip_atomic_compare_exchange_strong(&fbar[32], &e1, 0u, __ATOMIC_RELAXED,
                                         __ATOMIC_RELAXED, __HIP_MEMORY_SCOPE_AGENT);
    uint32_t e2 = 0xAAAAAAAAu;
    __hip_atomic_compare_exchange_strong(gcnt, &e2, 0u, __ATOMIC_RELAXED,
                                         __ATOMIC_RELAXED, __HIP_MEMORY_SCOPE_AGENT);
  }
  // zero own h slice in buffer A with WRITE-THROUGH stores (LLC-visible at t=0)
  store16_llc(hga + (size_t)(b0 + orow) * 2048u + n0 + ocol, (u32x4){0u, 0u, 0u, 0u});
  if (cb == 0)
    for (uint32_t e = tid; e < 320u; e += TPB) out[b0 * 10u + e] = 0.0f;

  // ---- W_res slice -> VGPRs (persist 512 steps): wave's 512-K x 64-N ----
  half8 wb[16][4];                 // 256 VGPRs
  #pragma unroll
  for (uint32_t kk = 0; kk < 16u; ++kk)
    #pragma unroll
    for (uint32_t nt = 0; nt < 4u; ++nt)
      #pragma unroll
      for (uint32_t j = 0; j < 8u; ++j)
        wb[kk][nt][j] = (f16)Wres[(size_t)(wv * 512u + kk * 32u + kb + j) * 2048u
                                  + n0 + nt * 16u + lrow];
  // ---- W_in split hi/lo, this wave's 16-col group (nt == wv) ----
  half8 wiH[2], wiL[2];
  #pragma unroll
  for (uint32_t kx = 0; kx < 2u; ++kx)
    #pragma unroll
    for (uint32_t j = 0; j < 8u; ++j) {
      float v = Win[(size_t)(kx * 32u + kb + j) * 2048u + n0 + wv * 16u + lrow];
      f16 hh = (f16)v; wiH[kx][j] = hh; wiL[kx][j] = (f16)(v - (float)hh);
    }

  f32x4 acc[2][4], xa[2];
  #pragma unroll
  for (uint32_t mt = 0; mt < 2u; ++mt) {
    xa[mt] = (f32x4){0.f, 0.f, 0.f, 0.f};
    #pragma unroll
    for (uint32_t nt = 0; nt < 4u; ++nt) acc[mt][nt] = (f32x4){0.f, 0.f, 0.f, 0.f};
  }
  float m8[8];
  #pragma unroll
  for (int j = 0; j < 8; ++j) m8[j] = 0.0f;

  // ---- swizzle (XOR involution; inverse pre-applied to LLC-read source) ----
  // LDS holds h[r][c-byte] at r*512 + (c ^ ((r&7)<<4)), c in [0,512).
  const uint32_t ri = l >> 5u;                               // row parity in DMA pair
  const uint32_t cc = ((l & 31u) * 16u) ^ (ri << 4u);        // stage-side byte col
  const uint32_t bc = (q * 16u) ^ ((l & 7u) << 4u);          // read-side XOR term
  const uint32_t rb0 = lrow * 512u, rb1 = (16u + lrow) * 512u;

#define STAGE(sb, lb) { \
    const char* gsx = (const char*)hr + (size_t)(b0 + ri) * 4096u \
                      + wv * 1024u + (sb) * 512u; \
    _Pragma("unroll") \
    for (uint32_t d = 0; d < 16u; ++d) \
      gload_lds16_llc(gsx + (size_t)d * 8192u + (cc ^ (((2u * d) & 7u) << 4u)), \
                      (lb) + d * 1024u); }

#define GSUB(lb, base) { \
    _Pragma("unroll") \
    for (uint32_t kk = 0; kk < 8u; ++kk) { \
      half8 a0 = *(const half8*)((lb) + rb0 + ((kk * 64u) ^ bc)); \
      half8 a1 = *(const half8*)((lb) + rb1 + ((kk * 64u) ^ bc)); \
      _Pragma("unroll") \
      for (uint32_t nt = 0; nt < 4u; ++nt) { \
        acc[0][nt] = __builtin_amdgcn_mfma_f32_16x16x32_f16(a0, wb[(base) + kk][nt], acc[0][nt], 0, 0, 0); \
        acc[1][nt] = __builtin_amdgcn_mfma_f32_16x16x32_f16(a1, wb[(base) + kk][nt], acc[1][nt], 0, 0, 0); \
      } } }

  // x_t @ W_in (split f16: xh*Wh + xl*Wh + xh*Wl), this wave's 16 cols only
#define XPROJ(tt) { \
    _Pragma("unroll") \
    for (uint32_t mt = 0; mt < 2u; ++mt) { \
      const float* px = x + ((size_t)(b0 + mt * 16u + lrow) * 512u + (uint32_t)(tt)) * 64u + kb; \
      _Pragma("unroll") \
      for (uint32_t kx = 0; kx < 2u; ++kx) { \
        float4 va = *(const float4*)(px + kx * 32u); \
        float4 vb = *(const float4*)(px + kx * 32u + 4u); \
        float fv[8] = {va.x, va.y, va.z, va.w, vb.x, vb.y, vb.z, vb.w}; \
        half8 xh, xl; \
        _Pragma("unroll") \
        for (int j = 0; j < 8; ++j) { \
          f16 hh = (f16)fv[j]; xh[j] = hh; xl[j] = (f16)(fv[j] - (float)hh); } \
        xa[mt] = __builtin_amdgcn_mfma_f32_16x16x32_f16(xh, wiH[kx], xa[mt], 0, 0, 0); \
        xa[mt] = __builtin_amdgcn_mfma_f32_16x16x32_f16(xl, wiH[kx], xa[mt], 0, 0, 0); \
        xa[mt] = __builtin_amdgcn_mfma_f32_16x16x32_f16(xh, wiL[kx], xa[mt], 0, 0, 0); \
      } } }

  XPROJ(0);                       // t=0 projection hides flatbar skew
  flatbar(&fbar[0], &fbar[32]);   // also flushes h-zeros / counter inits

  float* part = (float*)smem;     // split-K partials [128][68] f32 (overlay bufs)

  for (int t = 0; t < 512; ++t) {
    const f16* hr = (t & 1) ? hgb : hga;
    f16*       hw = (t & 1) ? hga : hgb;

    // ---- h @ W_res: self-synchronized per wave (own DMAs -> own buf) ----
    STAGE(0u, lb0);
    STAGE(1u, lb1);
    WAITVM(16);                   // sub-chunk 0 landed (exactly 32 in flight)
    GSUB(lb0, 0u);
    WAITVM(0);                    // sub-chunk 1 landed
    GSUB(lb1, 8u);
    __syncthreads();              // S1: all waves done reading staging bufs

    // ---- write split-K partials (+ fold x-projection where nt==wv) ----
    #pragma unroll
    for (uint32_t mt = 0; mt < 2u; ++mt)
      #pragma unroll
      for (uint32_t nt = 0; nt < 4u; ++nt)
        #pragma unroll
        for (uint32_t r = 0; r < 4u; ++r) {
          float v = acc[mt][nt][r] + ((nt == wv) ? xa[mt][r] : 0.0f);
          part[(wv * 32u + mt * 16u + q * 4u + r) * 68u + nt * 16u + lrow] = v;
          acc[mt][nt][r] = 0.0f;
        }
    #pragma unroll
    for (uint32_t mt = 0; mt < 2u; ++mt)
      #pragma unroll
      for (uint32_t r = 0; r < 4u; ++r) xa[mt][r] = 0.0f;
    __syncthreads();              // S2: partials visible

    // ---- reduce 4 partials (float4 reads), tanh, leaky update ----
    {
      const float* pr = part + orow * 68u + ocol;
      float4 sa = *(const float4*)(pr);
      float4 sb = *(const float4*)(pr + 4u);
      #pragma unroll
      for (uint32_t p = 1; p < 4u; ++p) {
        float4 ua = *(const float4*)(pr + p * 2176u);
        float4 ub = *(const float4*)(pr + p * 2176u + 4u);
        sa.x += ua.x; sa.y += ua.y; sa.z += ua.z; sa.w += ua.w;
        sb.x += ub.x; sb.y += ub.y; sb.z += ub.z; sb.w += ub.w;
      }
      float sv[8] = {sa.x, sa.y, sa.z, sa.w, sb.x, sb.y, sb.z, sb.w};
      #pragma unroll
      for (int j = 0; j < 8; ++j) m8[j] = 0.5f * m8[j] + 0.5f * ftanh(sv[j]);
    }

    if (t != 511) {
      // publish f16 state write-through (16B/thread, coalesced, -> LLC)
      half8 hv;
      #pragma unroll
      for (int j = 0; j < 8; ++j) hv[j] = (f16)m8[j];
      store16_llc(hw + (size_t)(b0 + orow) * 2048u + n0 + ocol, *(u32x4*)&hv);
      __syncthreads();            // S3: vmcnt(0) -> stores complete in LLC
      if (tid == 0)               // arrive: monotonic, no reset, no fences
        __hip_atomic_fetch_add(gcnt, 1u, __ATOMIC_RELAXED, __HIP_MEMORY_SCOPE_AGENT);
      XPROJ(t + 1);               // overlap barrier latency with next x-proj
      if (tid == 0) {
        const uint32_t tgt = 32u * ((uint32_t)t + 1u);
        while (__hip_atomic_load(gcnt, __ATOMIC_RELAXED, __HIP_MEMORY_SCOPE_AGENT) < tgt)
          __builtin_amdgcn_s_sleep(2);
      }
      __syncthreads();            // S4: whole WG sees h ready
    }
  }

  // ---- readout: out = h_last @ W_out + b_out ----
  {
    float* rsc = (float*)(smem + 40960u);   // [256 threads][10] f32, disjoint from part
    float ps[10];
    #pragma unroll
    for (int o = 0; o < 10; ++o) ps[o] = 0.0f;
    #pragma unroll
    for (int j = 0; j < 8; ++j) {
      float mj = m8[j];
      #pragma unroll
      for (int o = 0; o < 10; ++o)
        ps[o] += mj * Wout[(size_t)(n0 + ocol + j) * 10u + o];
    }
    #pragma unroll
    for (int o = 0; o < 10; ++o) rsc[tid * 10u + o] = ps[o];
    __syncthreads();
    for (uint32_t e = tid; e < 320u; e += TPB) {
      uint32_t row = e / 10u, o = e - row * 10u;
      float s = 0.0f;
      #pragma unroll
      for (uint32_t k = 0; k < 8u; ++k) s += rsc[(row * 8u + k) * 10u + o];
      if (cb == 0) s += bout[o];          // bias exactly once per (b,o)
      atomicAdd(&out[(size_t)(b0 + row) * 10u + o], s);
    }
  }
}

extern "C" void kernel_launch(void* const* d_in, const int* in_sizes, int n_in,
                              void* d_out, int out_size, void* d_ws, size_t ws_size,
                              hipStream_t stream) {
  (void)in_sizes; (void)n_in; (void)out_size; (void)ws_size;
  const float* x    = (const float*)d_in[0];
  const float* Win  = (const float*)d_in[1];
  const float* Wres = (const float*)d_in[2];
  const float* Wout = (const float*)d_in[3];
  const float* bout = (const float*)d_in[4];
  float* out = (float*)d_out;

  f16*      hga  = (f16*)d_ws;                                   // 1 MiB
  f16*      hgb  = (f16*)((char*)d_ws + (1u << 20));             // 1 MiB
  uint32_t* scnt = (uint32_t*)((char*)d_ws + (2u << 20));        // 8 x 64B counters
  uint32_t* fbar = (uint32_t*)((char*)d_ws + (2u << 20) + 4096u);

  (void)hipFuncSetAttribute((const void*)esn_persistent_kernel,
                            hipFuncAttributeMaxDynamicSharedMemorySize, LDS_BYTES);

  hipLaunchKernelGGL(esn_persistent_kernel, dim3(NWG), dim3(TPB), LDS_BYTES, stream,
                     x, Win, Wres, Wout, bout, out, hga, hgb, scnt, fbar);
}